// Round 14
// baseline (1171.582 us; speedup 1.0000x reference)
//
#include <hip/hip_runtime.h>
#include <math.h>

#define N_NODES 10000
#define L_LEN   256
#define D_DIM   32
#define K_NBR   32
#define NTOT    (N_NODES * L_LEN)
#define EPS_BN  1e-5f
#define NBATCH  157            // ceil(10000/64)
#define SENT    (~0ULL)

__device__ __forceinline__ float silu_f(float x) {
    return x / (1.0f + expf(-x));
}

// ---------- kernel 1: global sum & sumsq of pop ----------
__global__ void stats_kernel(const float* __restrict__ pop, float* __restrict__ stats) {
    __shared__ float s1[256], s2[256];
    int t = threadIdx.x;
    float a = 0.f, b = 0.f;
    for (int idx = blockIdx.x * 256 + t; idx < NTOT; idx += gridDim.x * 256) {
        float v = pop[idx];
        a += v; b += v * v;
    }
    s1[t] = a; s2[t] = b;
    __syncthreads();
    for (int s = 128; s > 0; s >>= 1) {
        if (t < s) { s1[t] += s1[t + s]; s2[t] += s2[t + s]; }
        __syncthreads();
    }
    if (t == 0) { atomicAdd(&stats[0], s1[0]); atomicAdd(&stats[1], s2[0]); }
}

// ---------- kernel 2: featurize (BN folded to global scalar stats) ----------
__global__ void feat_kernel(const float* __restrict__ pop,
                            const float* __restrict__ conv_w,
                            const float* __restrict__ conv_b,
                            const float* __restrict__ gamma,
                            const float* __restrict__ beta,
                            const float* __restrict__ stats,
                            float* __restrict__ X,
                            float* __restrict__ SQ) {
    __shared__ float row[L_LEN];
    __shared__ float part[256];
    int i = blockIdx.x;
    int t = threadIdx.x;
    row[t] = pop[i * L_LEN + t];
    __syncthreads();
    int d = t & 31, g = t >> 5;
    float M  = stats[0] * (1.0f / NTOT);
    float Vc = stats[1] * (1.0f / NTOT) - M * M;
    float w = conv_w[d], b = conv_b[d];
    float mean = fmaf(w, M, b);
    float var  = w * w * Vc;
    float sc = gamma[d] / sqrtf(var + EPS_BN);
    float bt = beta[d];
    float acc = 0.f;
    int l0 = g * 32;
    #pragma unroll
    for (int l = 0; l < 32; ++l) {
        float y = fmaf(row[l0 + l], w, b);
        float z = fmaf(y - mean, sc, bt);
        acc += silu_f(z);
    }
    part[t] = acc;
    __syncthreads();
    if (t < 32) {
        float s = 0.f;
        #pragma unroll
        for (int gg = 0; gg < 8; ++gg) s += part[gg * 32 + t];
        float xv = s * (1.0f / L_LEN);
        X[i * D_DIM + t] = xv;
        part[t] = xv;
    }
    __syncthreads();
    if (t == 0) {
        float sq = 0.f;
        #pragma unroll
        for (int dd = 0; dd < 32; ++dd) sq += part[dd] * part[dd];
        SQ[i] = sq;
    }
}

// ---------- helpers for kNN ----------
__device__ __forceinline__ float dot32(const float4* __restrict__ xp,
                                       const float4* __restrict__ qr) {
    float a = 0.f;
    #pragma unroll
    for (int i = 0; i < 8; ++i) {
        float4 v = xp[i]; float4 w = qr[i];
        a = fmaf(v.x, w.x, a); a = fmaf(v.y, w.y, a);
        a = fmaf(v.z, w.z, a); a = fmaf(v.w, w.w, a);
    }
    return a;
}

__device__ __forceinline__ unsigned long long wave_min64(unsigned long long v) {
    #pragma unroll
    for (int off = 32; off > 0; off >>= 1) {
        unsigned long long o = __shfl_xor(v, off);
        v = o < v ? o : v;
    }
    return v;
}

// sorted 4-deep ascending insert (pure VALU, per-lane private)
#define INS4(l0, l1, l2, l3, key) do { \
    if ((key) < (l3)) { \
        if ((key) < (l2)) { (l3) = (l2); \
            if ((key) < (l1)) { (l2) = (l1); \
                if ((key) < (l0)) { (l1) = (l0); (l0) = (key); } \
                else (l1) = (key); \
            } else (l2) = (key); \
        } else (l3) = (key); \
    } } while (0)

// rare refill: rescan lane's stripe (c = b*64+lane), keep keys > last
__device__ void refill_lane(const float* __restrict__ X,
                            const float* __restrict__ SQ,
                            const float4* __restrict__ qr, float sqq, int self,
                            int lane, unsigned long long last,
                            unsigned long long &l0, unsigned long long &l1,
                            unsigned long long &l2, unsigned long long &l3) {
    l0 = l1 = l2 = l3 = SENT;
    for (int b = 0; b < NBATCH; ++b) {
        int c = b * 64 + lane;
        if (c < N_NODES && c != self) {
            float acc = dot32((const float4*)(X + (size_t)c * D_DIM), qr);
            float d2 = (sqq + SQ[c]) - 2.0f * acc;
            unsigned int u = __float_as_uint(d2);
            u ^= (u & 0x80000000u) ? 0xFFFFFFFFu : 0x80000000u;
            unsigned long long key = ((unsigned long long)u << 32) | (unsigned int)c;
            if (key > last) INS4(l0, l1, l2, l3, key);
        }
    }
}

// ---------- kernel 3: kNN — per-lane top-4 + 32-round wave-min extraction ----------
// 4 queries/wave (shared candidate reads); unique u64 keys (d2key<<32|idx) give
// top_k's exact value-then-lowest-index order. No LDS, no atomics, no barriers.
__global__ __launch_bounds__(256) void knn_extract(const float* __restrict__ X,
                                                   const float* __restrict__ SQ,
                                                   int* __restrict__ NBR) {
    int lane = threadIdx.x & 63;
    int wv   = threadIdx.x >> 6;
    int q0   = blockIdx.x * 16 + wv * 4;

    const float4* qr0 = (const float4*)(X + (size_t)(q0 + 0) * D_DIM);
    const float4* qr1 = (const float4*)(X + (size_t)(q0 + 1) * D_DIM);
    const float4* qr2 = (const float4*)(X + (size_t)(q0 + 2) * D_DIM);
    const float4* qr3 = (const float4*)(X + (size_t)(q0 + 3) * D_DIM);
    float sq0 = SQ[q0 + 0], sq1 = SQ[q0 + 1], sq2 = SQ[q0 + 2], sq3 = SQ[q0 + 3];

    unsigned long long a0 = SENT, a1 = SENT, a2 = SENT, a3 = SENT;   // q0 list
    unsigned long long b0 = SENT, b1 = SENT, b2 = SENT, b3 = SENT;   // q1 list
    unsigned long long c0 = SENT, c1 = SENT, c2 = SENT, c3 = SENT;   // q2 list
    unsigned long long d0 = SENT, d1 = SENT, d2_ = SENT, d3 = SENT;  // q3 list

    // ---- build: stream candidates, per-lane top-4 per query ----
    for (int b = 0; b < NBATCH; ++b) {
        int c = b * 64 + lane;
        bool valid = c < N_NODES;
        float4 xr[8];
        const float4* xp = (const float4*)(X + (size_t)c * D_DIM);
        if (valid) {
            #pragma unroll
            for (int i = 0; i < 8; ++i) xr[i] = xp[i];
        } else {
            #pragma unroll
            for (int i = 0; i < 8; ++i) xr[i] = make_float4(0.f, 0.f, 0.f, 0.f);
        }
        float sqc = valid ? SQ[c] : 0.f;

        float s0 = 0.f, s1 = 0.f, s2 = 0.f, s3 = 0.f;
        #pragma unroll
        for (int i = 0; i < 8; ++i) {
            float4 v = xr[i];
            float4 w0 = qr0[i], w1 = qr1[i], w2 = qr2[i], w3 = qr3[i];
            s0 = fmaf(v.x, w0.x, s0); s0 = fmaf(v.y, w0.y, s0);
            s0 = fmaf(v.z, w0.z, s0); s0 = fmaf(v.w, w0.w, s0);
            s1 = fmaf(v.x, w1.x, s1); s1 = fmaf(v.y, w1.y, s1);
            s1 = fmaf(v.z, w1.z, s1); s1 = fmaf(v.w, w1.w, s1);
            s2 = fmaf(v.x, w2.x, s2); s2 = fmaf(v.y, w2.y, s2);
            s2 = fmaf(v.z, w2.z, s2); s2 = fmaf(v.w, w2.w, s2);
            s3 = fmaf(v.x, w3.x, s3); s3 = fmaf(v.y, w3.y, s3);
            s3 = fmaf(v.z, w3.z, s3); s3 = fmaf(v.w, w3.w, s3);
        }

        #define MKKEY(sqq, acc, self, kout) do { \
            float d2v = ((sqq) + sqc) - 2.0f * (acc); \
            unsigned int u = __float_as_uint(d2v); \
            u ^= (u & 0x80000000u) ? 0xFFFFFFFFu : 0x80000000u; \
            kout = ((unsigned long long)u << 32) | (unsigned int)c; \
            if (!valid || c == (self)) kout = SENT; \
        } while (0)

        unsigned long long k;
        MKKEY(sq0, s0, q0 + 0, k); INS4(a0, a1, a2, a3, k);
        MKKEY(sq1, s1, q0 + 1, k); INS4(b0, b1, b2, b3, k);
        MKKEY(sq2, s2, q0 + 2, k); INS4(c0, c1, c2, c3, k);
        MKKEY(sq3, s3, q0 + 3, k); INS4(d0, d1, d2_, d3, k);
        #undef MKKEY
    }

    // ---- extraction: 32 rounds, 4 independent butterfly-min chains ----
    int out0 = 0, out1 = 0, out2 = 0, out3 = 0;
    unsigned long long la = SENT, lb = SENT, lc = SENT, ld = SENT;  // last popped
    bool na = false, nb = false, nc = false, nd = false;            // need refill

    #pragma unroll 1
    for (int r = 0; r < K_NBR; ++r) {
        unsigned long long m0 = wave_min64(a0);
        unsigned long long m1 = wave_min64(b0);
        unsigned long long m2 = wave_min64(c0);
        unsigned long long m3 = wave_min64(d0);

        if (lane == r) {
            out0 = (int)(unsigned int)m0;
            out1 = (int)(unsigned int)m1;
            out2 = (int)(unsigned int)m2;
            out3 = (int)(unsigned int)m3;
        }
        // keys unique -> exactly one lane matches each min
        if (a0 == m0) { la = m0; a0 = a1; a1 = a2; a2 = a3; a3 = SENT; na = (a0 == SENT); }
        if (b0 == m1) { lb = m1; b0 = b1; b1 = b2; b2 = b3; b3 = SENT; nb = (b0 == SENT); }
        if (c0 == m2) { lc = m2; c0 = c1; c1 = c2; c2 = c3; c3 = SENT; nc = (c0 == SENT); }
        if (d0 == m3) { ld = m3; d0 = d1; d1 = d2_; d2_ = d3; d3 = SENT; nd = (d0 == SENT); }

        if (__any(na)) { if (na) refill_lane(X, SQ, qr0, sq0, q0 + 0, lane, la, a0, a1, a2, a3); na = false; }
        if (__any(nb)) { if (nb) refill_lane(X, SQ, qr1, sq1, q0 + 1, lane, lb, b0, b1, b2, b3); nb = false; }
        if (__any(nc)) { if (nc) refill_lane(X, SQ, qr2, sq2, q0 + 2, lane, lc, c0, c1, c2, c3); nc = false; }
        if (__any(nd)) { if (nd) refill_lane(X, SQ, qr3, sq3, q0 + 3, lane, ld, d0, d1, d2_, d3); nd = false; }
    }

    if (lane < K_NBR) {
        NBR[(size_t)(q0 + 0) * K_NBR + lane] = out0;
        NBR[(size_t)(q0 + 1) * K_NBR + lane] = out1;
        NBR[(size_t)(q0 + 2) * K_NBR + lane] = out2;
        NBR[(size_t)(q0 + 3) * K_NBR + lane] = out3;
    }
}

// ---------- kernel 4: fused GCN layer ----------
// By linearity: silu( ((x_i + sum_nbr x_j)/33) @ W + b ). One kernel per layer.
__global__ void gcn_fused(const float* __restrict__ Xin, const int* __restrict__ NBR,
                          const float* __restrict__ W, const float* __restrict__ bias,
                          float* __restrict__ Xout) {
    __shared__ float Ws[D_DIM * D_DIM];
    __shared__ float sAgg[8][D_DIM];
    __shared__ int nb[8][K_NBR];
    int t = threadIdx.x, g = t >> 5, d = t & 31;
    #pragma unroll
    for (int q = 0; q < 4; ++q) Ws[q * 256 + t] = W[q * 256 + t];
    int i = blockIdx.x * 8 + g;
    nb[g][d] = NBR[i * K_NBR + d];
    __syncthreads();
    float s = Xin[i * D_DIM + d];
    #pragma unroll 8
    for (int e = 0; e < K_NBR; ++e) s += Xin[nb[g][e] * D_DIM + d];
    sAgg[g][d] = s;
    __syncthreads();
    float acc = 0.f;
    #pragma unroll
    for (int m = 0; m < D_DIM; ++m)
        acc = fmaf(sAgg[g][m], Ws[m * D_DIM + d], acc);
    float v = fmaf(acc, 1.0f / 33.0f, bias[d]);   // deg == 33 for every node
    Xout[i * D_DIM + d] = silu_f(v);
}

// ---------- kernel 5: fused out-proj + aggregate + softmax ----------
__global__ void out_final(const float* __restrict__ Xin, const int* __restrict__ NBR,
                          const float* __restrict__ Wout, const float* __restrict__ out_b,
                          float* __restrict__ out) {
    __shared__ float Ws[D_DIM * 3];
    __shared__ float sAgg[8][D_DIM];
    __shared__ int nb[8][K_NBR];
    int t = threadIdx.x, g = t >> 5, d = t & 31;
    if (t < D_DIM * 3) Ws[t] = Wout[t];
    int i = blockIdx.x * 8 + g;
    nb[g][d] = NBR[i * K_NBR + d];
    __syncthreads();
    float s = Xin[i * D_DIM + d];
    #pragma unroll 8
    for (int e = 0; e < K_NBR; ++e) s += Xin[nb[g][e] * D_DIM + d];
    sAgg[g][d] = s;
    __syncthreads();
    if (d < 3) {
        float v[3];
        #pragma unroll
        for (int c = 0; c < 3; ++c) {
            float a = 0.f;
            #pragma unroll
            for (int m = 0; m < D_DIM; ++m) a = fmaf(sAgg[g][m], Ws[m * 3 + c], a);
            v[c] = fmaf(a, 1.0f / 33.0f, out_b[c]);
        }
        float mx = fmaxf(v[0], fmaxf(v[1], v[2]));
        float e0 = expf(v[0] - mx), e1 = expf(v[1] - mx), e2 = expf(v[2] - mx);
        out[i * 3 + d] = expf(v[d] - mx) / (e0 + e1 + e2);
    }
}

extern "C" void kernel_launch(void* const* d_in, const int* in_sizes, int n_in,
                              void* d_out, int out_size, void* d_ws, size_t ws_size,
                              hipStream_t stream) {
    const float* pop    = (const float*)d_in[0];
    const float* conv_w = (const float*)d_in[1];
    const float* conv_b = (const float*)d_in[2];
    const float* gamma  = (const float*)d_in[3];
    const float* beta   = (const float*)d_in[4];
    const float* gcn_ws = (const float*)d_in[5];
    const float* gcn_bs = (const float*)d_in[6];
    const float* out_w  = (const float*)d_in[7];
    const float* out_b  = (const float*)d_in[8];

    char* ws = (char*)d_ws;
    const size_t o_stats = 0;
    const size_t o_X     = 256;
    const size_t o_SQ    = o_X + 1280000;
    const size_t o_H     = o_SQ + 40192;
    const size_t o_NBR   = o_H + 1280000;

    float* stats = (float*)(ws + o_stats);
    float* X     = (float*)(ws + o_X);
    float* SQ    = (float*)(ws + o_SQ);
    float* H     = (float*)(ws + o_H);
    int*   NBR   = (int*)  (ws + o_NBR);
    float* out   = (float*)d_out;

    (void)hipMemsetAsync(stats, 0, 2 * sizeof(float), stream);
    stats_kernel<<<512, 256, 0, stream>>>(pop, stats);
    feat_kernel<<<N_NODES, 256, 0, stream>>>(pop, conv_w, conv_b, gamma, beta, stats, X, SQ);

    knn_extract<<<N_NODES / 16, 256, 0, stream>>>(X, SQ, NBR);   // 625 blocks

    gcn_fused<<<N_NODES / 8, 256, 0, stream>>>(X, NBR, gcn_ws,        gcn_bs,      H);
    gcn_fused<<<N_NODES / 8, 256, 0, stream>>>(H, NBR, gcn_ws + 1024, gcn_bs + 32, X);
    gcn_fused<<<N_NODES / 8, 256, 0, stream>>>(X, NBR, gcn_ws + 2048, gcn_bs + 64, H);
    out_final<<<N_NODES / 8, 256, 0, stream>>>(H, NBR, out_w, out_b, out);
}

// Round 15
// 950.530 us; speedup vs baseline: 1.2326x; 1.2326x over previous
//
#include <hip/hip_runtime.h>
#include <math.h>

#define N_NODES 10000
#define L_LEN   256
#define D_DIM   32
#define K_NBR   32
#define NTOT    (N_NODES * L_LEN)
#define EPS_BN  1e-5f
#define NBATCH  157            // ceil(10000/64)
#define NPADF   10016          // fixup LDS row (mult of 256 > N_NODES)
#define SENT    (~0ULL)

__device__ __forceinline__ float silu_f(float x) {
    return x / (1.0f + expf(-x));
}

// ---------- kernel 1: global sum & sumsq of pop ----------
__global__ void stats_kernel(const float* __restrict__ pop, float* __restrict__ stats) {
    __shared__ float s1[256], s2[256];
    int t = threadIdx.x;
    float a = 0.f, b = 0.f;
    for (int idx = blockIdx.x * 256 + t; idx < NTOT; idx += gridDim.x * 256) {
        float v = pop[idx];
        a += v; b += v * v;
    }
    s1[t] = a; s2[t] = b;
    __syncthreads();
    for (int s = 128; s > 0; s >>= 1) {
        if (t < s) { s1[t] += s1[t + s]; s2[t] += s2[t + s]; }
        __syncthreads();
    }
    if (t == 0) { atomicAdd(&stats[0], s1[0]); atomicAdd(&stats[1], s2[0]); }
}

// ---------- kernel 2: featurize (BN folded to global scalar stats) ----------
__global__ void feat_kernel(const float* __restrict__ pop,
                            const float* __restrict__ conv_w,
                            const float* __restrict__ conv_b,
                            const float* __restrict__ gamma,
                            const float* __restrict__ beta,
                            const float* __restrict__ stats,
                            float* __restrict__ X,
                            float* __restrict__ SQ) {
    __shared__ float row[L_LEN];
    __shared__ float part[256];
    int i = blockIdx.x;
    int t = threadIdx.x;
    row[t] = pop[i * L_LEN + t];
    __syncthreads();
    int d = t & 31, g = t >> 5;
    float M  = stats[0] * (1.0f / NTOT);
    float Vc = stats[1] * (1.0f / NTOT) - M * M;
    float w = conv_w[d], b = conv_b[d];
    float mean = fmaf(w, M, b);
    float var  = w * w * Vc;
    float sc = gamma[d] / sqrtf(var + EPS_BN);
    float bt = beta[d];
    float acc = 0.f;
    int l0 = g * 32;
    #pragma unroll
    for (int l = 0; l < 32; ++l) {
        float y = fmaf(row[l0 + l], w, b);
        float z = fmaf(y - mean, sc, bt);
        acc += silu_f(z);
    }
    part[t] = acc;
    __syncthreads();
    if (t < 32) {
        float s = 0.f;
        #pragma unroll
        for (int gg = 0; gg < 8; ++gg) s += part[gg * 32 + t];
        float xv = s * (1.0f / L_LEN);
        X[i * D_DIM + t] = xv;
        part[t] = xv;
    }
    __syncthreads();
    if (t == 0) {
        float sq = 0.f;
        #pragma unroll
        for (int dd = 0; dd < 32; ++dd) sq += part[dd] * part[dd];
        SQ[i] = sq;
    }
}

// ---------- helpers ----------
__device__ __forceinline__ float dot32(const float4* __restrict__ xp,
                                       const float4* __restrict__ qr) {
    float a = 0.f;
    #pragma unroll
    for (int i = 0; i < 8; ++i) {
        float4 v = xp[i]; float4 w = qr[i];
        a = fmaf(v.x, w.x, a); a = fmaf(v.y, w.y, a);
        a = fmaf(v.z, w.z, a); a = fmaf(v.w, w.w, a);
    }
    return a;
}

__device__ __forceinline__ unsigned long long wave_min64(unsigned long long v) {
    #pragma unroll
    for (int off = 32; off > 0; off >>= 1) {
        unsigned long long o = __shfl_xor(v, off);
        v = o < v ? o : v;
    }
    return v;
}

// sorted 6-deep ascending insert (pure VALU, per-lane private)
#define INS6(l0, l1, l2, l3, l4, l5, key) do { \
    if ((key) < (l5)) { \
        if ((key) < (l4)) { (l5) = (l4); \
            if ((key) < (l3)) { (l4) = (l3); \
                if ((key) < (l2)) { (l3) = (l2); \
                    if ((key) < (l1)) { (l2) = (l1); \
                        if ((key) < (l0)) { (l1) = (l0); (l0) = (key); } \
                        else (l1) = (key); \
                    } else (l2) = (key); \
                } else (l3) = (key); \
            } else (l4) = (key); \
        } else (l5) = (key); \
    } } while (0)

// ---------- kernel 3: kNN — per-lane top-6 + 32-round wave-min extraction ----------
// 4 queries/wave share candidate reads. No LDS/atomics/barriers; NO in-loop
// refill (that spilled in R14). Rare dry lanes (~6e-4/query) set BAD[q]; the
// fixup kernel redoes those rows exactly. Unique u64 keys (d2key<<32|idx)
// reproduce top_k's value-then-lowest-index order.
__global__ __launch_bounds__(256) void knn_exact(const float* __restrict__ X,
                                                 const float* __restrict__ SQ,
                                                 int* __restrict__ NBR,
                                                 int* __restrict__ BAD) {
    int lane = threadIdx.x & 63;
    int wv   = threadIdx.x >> 6;
    int q0   = blockIdx.x * 16 + wv * 4;

    const float4* qr0 = (const float4*)(X + (size_t)(q0 + 0) * D_DIM);
    const float4* qr1 = (const float4*)(X + (size_t)(q0 + 1) * D_DIM);
    const float4* qr2 = (const float4*)(X + (size_t)(q0 + 2) * D_DIM);
    const float4* qr3 = (const float4*)(X + (size_t)(q0 + 3) * D_DIM);
    float sq0 = SQ[q0 + 0], sq1 = SQ[q0 + 1], sq2 = SQ[q0 + 2], sq3 = SQ[q0 + 3];

    unsigned long long a0 = SENT, a1 = SENT, a2 = SENT, a3 = SENT, a4 = SENT, a5 = SENT;
    unsigned long long b0 = SENT, b1 = SENT, b2 = SENT, b3 = SENT, b4 = SENT, b5 = SENT;
    unsigned long long c0 = SENT, c1 = SENT, c2 = SENT, c3 = SENT, c4 = SENT, c5 = SENT;
    unsigned long long e0 = SENT, e1 = SENT, e2 = SENT, e3 = SENT, e4 = SENT, e5 = SENT;

    // ---- build: stream candidates, per-lane top-6 per query ----
    for (int b = 0; b < NBATCH; ++b) {
        int c = b * 64 + lane;
        bool valid = c < N_NODES;
        float4 xr[8];
        const float4* xp = (const float4*)(X + (size_t)c * D_DIM);
        if (valid) {
            #pragma unroll
            for (int i = 0; i < 8; ++i) xr[i] = xp[i];
        } else {
            #pragma unroll
            for (int i = 0; i < 8; ++i) xr[i] = make_float4(0.f, 0.f, 0.f, 0.f);
        }
        float sqc = valid ? SQ[c] : 0.f;

        float s0 = 0.f, s1 = 0.f, s2 = 0.f, s3 = 0.f;
        #pragma unroll
        for (int i = 0; i < 8; ++i) {
            float4 v = xr[i];
            float4 w0 = qr0[i], w1 = qr1[i], w2 = qr2[i], w3 = qr3[i];
            s0 = fmaf(v.x, w0.x, s0); s0 = fmaf(v.y, w0.y, s0);
            s0 = fmaf(v.z, w0.z, s0); s0 = fmaf(v.w, w0.w, s0);
            s1 = fmaf(v.x, w1.x, s1); s1 = fmaf(v.y, w1.y, s1);
            s1 = fmaf(v.z, w1.z, s1); s1 = fmaf(v.w, w1.w, s1);
            s2 = fmaf(v.x, w2.x, s2); s2 = fmaf(v.y, w2.y, s2);
            s2 = fmaf(v.z, w2.z, s2); s2 = fmaf(v.w, w2.w, s2);
            s3 = fmaf(v.x, w3.x, s3); s3 = fmaf(v.y, w3.y, s3);
            s3 = fmaf(v.z, w3.z, s3); s3 = fmaf(v.w, w3.w, s3);
        }

        #define MKKEY(sqq, acc, self, kout) do { \
            float d2v = ((sqq) + sqc) - 2.0f * (acc); \
            unsigned int u = __float_as_uint(d2v); \
            u ^= (u & 0x80000000u) ? 0xFFFFFFFFu : 0x80000000u; \
            kout = ((unsigned long long)u << 32) | (unsigned int)c; \
            if (!valid || c == (self)) kout = SENT; \
        } while (0)

        unsigned long long k;
        MKKEY(sq0, s0, q0 + 0, k); INS6(a0, a1, a2, a3, a4, a5, k);
        MKKEY(sq1, s1, q0 + 1, k); INS6(b0, b1, b2, b3, b4, b5, k);
        MKKEY(sq2, s2, q0 + 2, k); INS6(c0, c1, c2, c3, c4, c5, k);
        MKKEY(sq3, s3, q0 + 3, k); INS6(e0, e1, e2, e3, e4, e5, k);
        #undef MKKEY
    }

    // ---- extraction: 32 rounds, 4 independent butterfly-min chains ----
    int out0 = 0, out1 = 0, out2 = 0, out3 = 0;
    #pragma unroll 1
    for (int r = 0; r < K_NBR; ++r) {
        unsigned long long m0 = wave_min64(a0);
        unsigned long long m1 = wave_min64(b0);
        unsigned long long m2 = wave_min64(c0);
        unsigned long long m3 = wave_min64(e0);
        if (lane == r) {
            out0 = (int)(unsigned int)m0;
            out1 = (int)(unsigned int)m1;
            out2 = (int)(unsigned int)m2;
            out3 = (int)(unsigned int)m3;
        }
        // unique keys -> exactly one lane matches each min; pop it
        if (a0 == m0) { a0 = a1; a1 = a2; a2 = a3; a3 = a4; a4 = a5; a5 = SENT; }
        if (b0 == m1) { b0 = b1; b1 = b2; b2 = b3; b3 = b4; b4 = b5; b5 = SENT; }
        if (c0 == m2) { c0 = c1; c1 = c2; c2 = c3; c3 = c4; c4 = c5; c5 = SENT; }
        if (e0 == m3) { e0 = e1; e1 = e2; e2 = e3; e3 = e4; e4 = e5; e5 = SENT; }
    }

    // ---- dry flags: lane exhausted its 6 entries => result may be inexact ----
    bool d0f = __any(a0 == SENT);
    bool d1f = __any(b0 == SENT);
    bool d2f = __any(c0 == SENT);
    bool d3f = __any(e0 == SENT);
    if (lane == 0) {
        if (d0f) BAD[q0 + 0] = 1;
        if (d1f) BAD[q0 + 1] = 1;
        if (d2f) BAD[q0 + 2] = 1;
        if (d3f) BAD[q0 + 3] = 1;
    }

    if (lane < K_NBR) {
        NBR[(size_t)(q0 + 0) * K_NBR + lane] = out0;
        NBR[(size_t)(q0 + 1) * K_NBR + lane] = out1;
        NBR[(size_t)(q0 + 2) * K_NBR + lane] = out2;
        NBR[(size_t)(q0 + 3) * K_NBR + lane] = out3;
    }
}

// ---------- kernel 3b: exact fixup for flagged queries (rare: ~1e-3) ----------
__global__ __launch_bounds__(256) void fixup_kernel(const float* __restrict__ X,
                                                    const float* __restrict__ SQ,
                                                    const int* __restrict__ BAD,
                                                    int* __restrict__ NBR) {
    int q = blockIdx.x;
    if (BAD[q] == 0) return;
    __shared__ unsigned int kk[NPADF];
    __shared__ unsigned long long red[4];
    __shared__ unsigned long long slast;
    int t = threadIdx.x;
    const float4* qr = (const float4*)(X + (size_t)q * D_DIM);
    float sqq = SQ[q];
    for (int c = t; c < NPADF; c += 256) {
        unsigned int u = 0xFFFFFFFFu;
        if (c < N_NODES && c != q) {
            float acc = dot32((const float4*)(X + (size_t)c * D_DIM), qr);
            float d2 = (sqq + SQ[c]) - 2.0f * acc;
            u = __float_as_uint(d2);
            u ^= (u & 0x80000000u) ? 0xFFFFFFFFu : 0x80000000u;
        }
        kk[c] = u;
    }
    if (t == 0) slast = 0ULL;            // composite 0 unreachable (d2 finite)
    __syncthreads();
    for (int r = 0; r < K_NBR; ++r) {
        unsigned long long last = slast;
        unsigned long long best = SENT;
        for (int c = t; c < NPADF; c += 256) {
            unsigned long long comp = ((unsigned long long)kk[c] << 32) | (unsigned int)c;
            if (comp > last && comp < best) best = comp;
        }
        best = wave_min64(best);
        if ((t & 63) == 0) red[t >> 6] = best;
        __syncthreads();
        if (t == 0) {
            unsigned long long m = red[0];
            #pragma unroll
            for (int i = 1; i < 4; ++i) m = red[i] < m ? red[i] : m;
            NBR[(size_t)q * K_NBR + r] = (int)(unsigned int)m;
            slast = m;
        }
        __syncthreads();
    }
}

// ---------- kernel 4: fused GCN layer ----------
__global__ void gcn_fused(const float* __restrict__ Xin, const int* __restrict__ NBR,
                          const float* __restrict__ W, const float* __restrict__ bias,
                          float* __restrict__ Xout) {
    __shared__ float Ws[D_DIM * D_DIM];
    __shared__ float sAgg[8][D_DIM];
    __shared__ int nb[8][K_NBR];
    int t = threadIdx.x, g = t >> 5, d = t & 31;
    #pragma unroll
    for (int q = 0; q < 4; ++q) Ws[q * 256 + t] = W[q * 256 + t];
    int i = blockIdx.x * 8 + g;
    nb[g][d] = NBR[i * K_NBR + d];
    __syncthreads();
    float s = Xin[i * D_DIM + d];
    #pragma unroll 8
    for (int e = 0; e < K_NBR; ++e) s += Xin[nb[g][e] * D_DIM + d];
    sAgg[g][d] = s;
    __syncthreads();
    float acc = 0.f;
    #pragma unroll
    for (int m = 0; m < D_DIM; ++m)
        acc = fmaf(sAgg[g][m], Ws[m * D_DIM + d], acc);
    float v = fmaf(acc, 1.0f / 33.0f, bias[d]);   // deg == 33 for every node
    Xout[i * D_DIM + d] = silu_f(v);
}

// ---------- kernel 5: fused out-proj + aggregate + softmax ----------
__global__ void out_final(const float* __restrict__ Xin, const int* __restrict__ NBR,
                          const float* __restrict__ Wout, const float* __restrict__ out_b,
                          float* __restrict__ out) {
    __shared__ float Ws[D_DIM * 3];
    __shared__ float sAgg[8][D_DIM];
    __shared__ int nb[8][K_NBR];
    int t = threadIdx.x, g = t >> 5, d = t & 31;
    if (t < D_DIM * 3) Ws[t] = Wout[t];
    int i = blockIdx.x * 8 + g;
    nb[g][d] = NBR[i * K_NBR + d];
    __syncthreads();
    float s = Xin[i * D_DIM + d];
    #pragma unroll 8
    for (int e = 0; e < K_NBR; ++e) s += Xin[nb[g][e] * D_DIM + d];
    sAgg[g][d] = s;
    __syncthreads();
    if (d < 3) {
        float v[3];
        #pragma unroll
        for (int c = 0; c < 3; ++c) {
            float a = 0.f;
            #pragma unroll
            for (int m = 0; m < D_DIM; ++m) a = fmaf(sAgg[g][m], Ws[m * 3 + c], a);
            v[c] = fmaf(a, 1.0f / 33.0f, out_b[c]);
        }
        float mx = fmaxf(v[0], fmaxf(v[1], v[2]));
        float ex0 = expf(v[0] - mx), ex1 = expf(v[1] - mx), ex2 = expf(v[2] - mx);
        out[i * 3 + d] = expf(v[d] - mx) / (ex0 + ex1 + ex2);
    }
}

extern "C" void kernel_launch(void* const* d_in, const int* in_sizes, int n_in,
                              void* d_out, int out_size, void* d_ws, size_t ws_size,
                              hipStream_t stream) {
    const float* pop    = (const float*)d_in[0];
    const float* conv_w = (const float*)d_in[1];
    const float* conv_b = (const float*)d_in[2];
    const float* gamma  = (const float*)d_in[3];
    const float* beta   = (const float*)d_in[4];
    const float* gcn_ws = (const float*)d_in[5];
    const float* gcn_bs = (const float*)d_in[6];
    const float* out_w  = (const float*)d_in[7];
    const float* out_b  = (const float*)d_in[8];

    char* ws = (char*)d_ws;
    const size_t o_stats = 0;
    const size_t o_X     = 256;
    const size_t o_SQ    = o_X + 1280000;
    const size_t o_H     = o_SQ + 40192;
    const size_t o_NBR   = o_H + 1280000;
    const size_t o_BAD   = o_NBR + 1280000;

    float* stats = (float*)(ws + o_stats);
    float* X     = (float*)(ws + o_X);
    float* SQ    = (float*)(ws + o_SQ);
    float* H     = (float*)(ws + o_H);
    int*   NBR   = (int*)  (ws + o_NBR);
    int*   BAD   = (int*)  (ws + o_BAD);
    float* out   = (float*)d_out;

    (void)hipMemsetAsync(stats, 0, 2 * sizeof(float), stream);
    (void)hipMemsetAsync(BAD, 0, N_NODES * sizeof(int), stream);
    stats_kernel<<<512, 256, 0, stream>>>(pop, stats);
    feat_kernel<<<N_NODES, 256, 0, stream>>>(pop, conv_w, conv_b, gamma, beta, stats, X, SQ);

    knn_exact<<<N_NODES / 16, 256, 0, stream>>>(X, SQ, NBR, BAD);   // 625 blocks
    fixup_kernel<<<N_NODES, 256, 0, stream>>>(X, SQ, BAD, NBR);     // flagged only

    gcn_fused<<<N_NODES / 8, 256, 0, stream>>>(X, NBR, gcn_ws,        gcn_bs,      H);
    gcn_fused<<<N_NODES / 8, 256, 0, stream>>>(H, NBR, gcn_ws + 1024, gcn_bs + 32, X);
    gcn_fused<<<N_NODES / 8, 256, 0, stream>>>(X, NBR, gcn_ws + 2048, gcn_bs + 64, H);
    out_final<<<N_NODES / 8, 256, 0, stream>>>(H, NBR, out_w, out_b, out);
}